// Round 2
// baseline (403.022 us; speedup 1.0000x reference)
//
#include <hip/hip_runtime.h>
#include <hip/hip_bf16.h>

// Problem constants (CRF: B=256 seqs, M=1024 steps, D=128 feat, N=26 labels)
#define CB 256
#define CM 1024
#define CD 128
#define CN 26

__device__ inline float rfl_f(float x) {
    return __int_as_float(__builtin_amdgcn_readfirstlane(__float_as_int(x)));
}

__device__ inline float fexp2(float x) {
#if __has_builtin(__builtin_amdgcn_exp2f)
    return __builtin_amdgcn_exp2f(x);
#else
    return exp2f(x);
#endif
}

__device__ inline float flog2(float x) {
#if __has_builtin(__builtin_amdgcn_logf)
    return __builtin_amdgcn_logf(x);
#else
    return log2f(x);
#endif
}

// ---------------------------------------------------------------------------
// Kernel 1: emissions E[r, a] = dot(X[r, :], W[a, :])  for r in [0, B*M)
// One thread per row. W addresses are wave-uniform -> scalar (K$) loads.
// ---------------------------------------------------------------------------
__global__ __launch_bounds__(256) void emit_kernel(const float* __restrict__ X,
                                                   const float* __restrict__ W,
                                                   float* __restrict__ E) {
    const int row = blockIdx.x * 256 + threadIdx.x;  // grid sized exactly
    const float4* __restrict__ x4 =
        reinterpret_cast<const float4*>(X + (size_t)row * CD);

    float acc[CN];
#pragma unroll
    for (int a = 0; a < CN; ++a) acc[a] = 0.f;

    for (int j = 0; j < CD / 4; ++j) {
        float4 xv = x4[j];
#pragma unroll
        for (int a = 0; a < CN; ++a) {
            float4 wv = *reinterpret_cast<const float4*>(W + a * CD + j * 4);
            acc[a] = fmaf(xv.x, wv.x, acc[a]);
            acc[a] = fmaf(xv.y, wv.y, acc[a]);
            acc[a] = fmaf(xv.z, wv.z, acc[a]);
            acc[a] = fmaf(xv.w, wv.w, acc[a]);
        }
    }

    float2* __restrict__ e2 = reinterpret_cast<float2*>(E + (size_t)row * CN);
#pragma unroll
    for (int a = 0; a < CN / 2; ++a)
        e2[a] = make_float2(acc[2 * a], acc[2 * a + 1]);
}

// ---------------------------------------------------------------------------
// Kernel 2: per-sequence forward recursion in prob space + unnorm gather.
// One wave (64 threads) per sequence.
// Lane layout: a = lane>>1 (output label), h = lane&1 (half of the b-sum).
// State f[b] (scaled forward message) replicated at lanes 2b, 2b+1.
// Each lane computes half the sum over b; the pair exchanges halves via
// shfl_xor(.,1) — THIS combine was the round-1 bug (missing -> -ln2/step).
// f_new[a] = 2^(ge[a]-c) * sum_b exp(T[b,a]) * f[b];  L += c (log2 scale).
// Renormalize by an exact power of two every 8 steps (no rounding error).
// ---------------------------------------------------------------------------
__global__ __launch_bounds__(64) void crf_forward_kernel(
    const float* __restrict__ E, const int* __restrict__ labels,
    const float* __restrict__ T, float* __restrict__ out) {
    const int s = blockIdx.x;
    const int l = threadIdx.x;
    const int base = s * CM;
    const float LOG2E = 1.4426950408889634f;
    const float LN2 = 0.6931471805599453f;

    int a = l >> 1;
    int h = l & 1;
    if (a > CN - 1) { a = CN - 1; h = 1; }  // lanes 52..63: duplicate work

    // ---- unnorm = sum_i e[i, y_i] + sum_i T[y_{i-1}, y_i] (all 64 lanes) ----
    float usum = 0.f;
    for (int i = l; i < CM; i += 64) {
        int y = labels[base + i];
        usum += E[(size_t)(base + i) * CN + y];
        if (i > 0) {
            int yp = labels[base + i - 1];
            usum += T[yp * CN + y];
        }
    }
#pragma unroll
    for (int off = 32; off > 0; off >>= 1) usum += __shfl_xor(usum, off, 64);

    // ---- transition matrix half-column slice, prob space ----
    float AT[13];
#pragma unroll
    for (int k = 0; k < 13; ++k) AT[k] = expf(T[(h * 13 + k) * CN + a]);

    const int hbase = h * CN;  // source lane base: lane 2b for b = h*13 + k

    // ---- init at i = 0 ----
    float e0 = E[(size_t)base * CN + a];
    float ge0 = LOG2E * e0;
    float c0 = rfl_f(ge0);
    float f = fexp2(ge0 - c0);
    float L = c0;

    float e_cur = E[(size_t)(base + 1) * CN + a];
    for (int i = 1; i < CM; ++i) {
        int nx = (i + 1 < CM) ? (i + 1) : (CM - 1);
        float e_nxt = E[(size_t)(base + nx) * CN + a];  // prefetch

        float ge = LOG2E * e_cur;
        float c = rfl_f(ge);
        float p = fexp2(ge - c);  // off the f-dependency chain

        // half-sum d = sum_{b in half h} AT[b,a] * f[b]
        float fb[13];
#pragma unroll
        for (int k = 0; k < 13; ++k) fb[k] = __shfl(f, hbase + 2 * k, 64);
        float d0 = 0.f, d1 = 0.f, d2 = 0.f, d3 = 0.f;
#pragma unroll
        for (int k = 0; k < 12; k += 4) {
            d0 = fmaf(AT[k + 0], fb[k + 0], d0);
            d1 = fmaf(AT[k + 1], fb[k + 1], d1);
            d2 = fmaf(AT[k + 2], fb[k + 2], d2);
            d3 = fmaf(AT[k + 3], fb[k + 3], d3);
        }
        d0 = fmaf(AT[12], fb[12], d0);
        float d = (d0 + d1) + (d2 + d3);

        // combine the two halves across the lane pair (the round-1 fix)
        d += __shfl_xor(d, 1, 64);

        f = p * d;
        L += c;

        if ((i & 7) == 0) {  // exact power-of-2 renormalization
            float fr = rfl_f(f);
            int k2 = (int)((__float_as_uint(fr) >> 23) & 255) - 127;
            f = ldexpf(f, -k2);
            L += (float)k2;
        }
        e_cur = e_nxt;
    }

    // ---- logZ = ln2 * (L + log2(sum_a f[a])), sum over even lanes 0..50 ----
    float fv = (h == 0) ? f : 0.f;
#pragma unroll
    for (int off = 32; off > 0; off >>= 1) fv += __shfl_xor(fv, off, 64);
    float logZ = LN2 * (L + flog2(fv));

    if (l == 0) atomicAdd(out, (usum - logZ) * (1.f / (float)CB));
}

extern "C" void kernel_launch(void* const* d_in, const int* in_sizes, int n_in,
                              void* d_out, int out_size, void* d_ws,
                              size_t ws_size, hipStream_t stream) {
    const float* X = (const float*)d_in[0];       // [B, M, D]
    const int* labels = (const int*)d_in[1];      // [B, M]
    const float* W = (const float*)d_in[2];       // [N, D]
    const float* T = (const float*)d_in[3];       // [N, N]
    float* out = (float*)d_out;                   // scalar
    float* E = (float*)d_ws;                      // [B*M, N] emissions

    hipMemsetAsync(d_out, 0, sizeof(float), stream);
    emit_kernel<<<(CB * CM) / 256, 256, 0, stream>>>(X, W, E);
    crf_forward_kernel<<<CB, 64, 0, stream>>>(E, labels, T, out);
}